// Round 9
// baseline (120.575 us; speedup 1.0000x reference)
//
#include <hip/hip_runtime.h>
#include <math.h>

#define BB 8
#define NN 64
#define SS 128
#define DD 512
#define HH 8
#define DKK 64
#define NSENT (BB * NN)          // 512
#define SENT_STRIDE (SS * DD)    // 65536 floats per sentence of x / out

// d_ws layout (floats)
#define WK_OFF 0                          // wk_t[8][512]        (16 KB)
#define XB_OFF 4096                       // xbar[512][8][512]   (8 MB)
#define Z_OFF  (XB_OFF + NSENT * HH * DD) // z[512][512]         (1 MB)
#define YY_OFF (Z_OFF + NSENT * DD)       // y[512][512]         (1 MB)

// ---------------------------------------------------------------------------
// DPP / swizzle helpers (imm operands must be ICE -> template params)
// ---------------------------------------------------------------------------
template <int CTRL>
__device__ __forceinline__ float ror_add(float v) {
    int r = __builtin_amdgcn_update_dpp(0, __float_as_int(v), CTRL, 0xf, 0xf, true);
    return v + __int_as_float(r);
}
// allreduce over each 16-lane row via rotate-by-1/2/4/8 (VALU pipe, no LDS)
__device__ __forceinline__ float row_allreduce(float v) {
    v = ror_add<0x121>(v);   // row_ror:1
    v = ror_add<0x122>(v);   // row_ror:2
    v = ror_add<0x124>(v);   // row_ror:4
    v = ror_add<0x128>(v);   // row_ror:8
    return v;
}
// broadcast from lane ((lane & 0x18) | H) within each 8-lane group
template <int H>
__device__ __forceinline__ float bcast8(float v) {
    return __int_as_float(
        __builtin_amdgcn_ds_swizzle(__float_as_int(v), (H << 5) | 0x18));
}

// ---------------------------------------------------------------------------
// K0: fold Wk with sent_q: wk_t[h][d] = sum_k Wk[d, h*64+k] * sent_q[h,k]
// (bk is softmax-shift-invariant; Wq/bq dead: token softmax is over a singleton)
// ---------------------------------------------------------------------------
__global__ void precompute_wk(const float* __restrict__ Wk,
                              const float* __restrict__ sq,
                              float* __restrict__ wk_t) {
    const int d = threadIdx.x;
    const int h = blockIdx.x;
    const float4* wrow = (const float4*)(Wk + (size_t)d * DD + h * DKK);
    const float4* sqv  = (const float4*)(sq + h * DKK);
    float acc = 0.f;
#pragma unroll
    for (int k = 0; k < DKK / 4; ++k) {
        float4 w = wrow[k], q = sqv[k];
        acc += w.x * q.x + w.y * q.y + w.z * q.z + w.w * q.w;
    }
    wk_t[h * DD + d] = acc;
}

// ---------------------------------------------------------------------------
// KA-fused: SINGLE PASS over x. One block per sentence, 256 thr (4 waves),
// wave owns 32 tokens. Lane holds dims d0..d0+7 (d0 = lane*8) of wk (8 heads)
// AND the accumulator acc[8h][8d]. Per token: dot -> DPP row-allreduce ->
// head-select -> xor16/32 -> exp -> swizzle-broadcast e_h -> in-register FMA.
// End: 2-stage LDS reduce across the 4 waves, normalize by per-head wsum.
// ---------------------------------------------------------------------------
__global__ __launch_bounds__(256, 2)
void ka_fused(const float* __restrict__ x, const int* __restrict__ mask,
              const float* __restrict__ wk_t, float* __restrict__ xbar)
{
    __shared__ float buf[2][HH][DD];   // 32 KB
    __shared__ float wsb[4][HH];
    __shared__ float rsh[HH];

    const int sent = blockIdx.x;
    const int t    = threadIdx.x;
    const int wave = t >> 6;
    const int lane = t & 63;
    const int d0   = lane * 8;

    // wk fragments: 8 heads x 8 dims (64 VGPRs)
    float4 wkA[HH], wkB[HH];
#pragma unroll
    for (int h = 0; h < HH; ++h) {
        wkA[h] = *(const float4*)(wk_t + h * DD + d0);
        wkB[h] = *(const float4*)(wk_t + h * DD + d0 + 4);
    }

    // mask bits for this wave's 32 tokens
    const int mv = (lane < 32) ? mask[sent * SS + wave * 32 + lane] : 0;
    const unsigned long long mb = __ballot(mv != 0);

    float4 accA[HH], accB[HH];
    float ws[HH];
#pragma unroll
    for (int h = 0; h < HH; ++h) {
        accA[h] = make_float4(0.f, 0.f, 0.f, 0.f);
        accB[h] = make_float4(0.f, 0.f, 0.f, 0.f);
        ws[h] = 0.f;
    }

    const float* xp = x + (size_t)sent * SENT_STRIDE + (size_t)(wave * 32) * DD + d0;

    float4 a0 = *(const float4*)(xp);
    float4 b0 = *(const float4*)(xp + 4);
    float4 a1 = *(const float4*)(xp + DD);
    float4 b1 = *(const float4*)(xp + DD + 4);

#pragma unroll 4
    for (int jp = 0; jp < 16; ++jp) {
        float4 na0, nb0, na1, nb1;
        if (jp < 15) {                       // prefetch next token pair
            const float* q = xp + (size_t)(2 * jp + 2) * DD;
            na0 = *(const float4*)(q);
            nb0 = *(const float4*)(q + 4);
            na1 = *(const float4*)(q + DD);
            nb1 = *(const float4*)(q + DD + 4);
        }

        // ---- dots for tokens 2jp, 2jp+1 ----
        float p0[HH], p1[HH];
#pragma unroll
        for (int h = 0; h < HH; ++h) {
            p0[h] = a0.x * wkA[h].x + a0.y * wkA[h].y + a0.z * wkA[h].z + a0.w * wkA[h].w
                  + b0.x * wkB[h].x + b0.y * wkB[h].y + b0.z * wkB[h].z + b0.w * wkB[h].w;
            p1[h] = a1.x * wkA[h].x + a1.y * wkA[h].y + a1.z * wkA[h].z + a1.w * wkA[h].w
                  + b1.x * wkB[h].x + b1.y * wkB[h].y + b1.z * wkB[h].z + b1.w * wkB[h].w;
        }
        // 16-lane row allreduce (VALU/DPP, no LDS)
#pragma unroll
        for (int h = 0; h < HH; ++h) {
            p0[h] = row_allreduce(p0[h]);
            p1[h] = row_allreduce(p1[h]);
        }
        // lane keeps head (lane&7); finish across the 4 rows
        const int r = lane & 7;
        float v0 = p0[0], v1 = p1[0];
#pragma unroll
        for (int h = 1; h < HH; ++h) {
            v0 = (r == h) ? p0[h] : v0;
            v1 = (r == h) ? p1[h] : v1;
        }
        v0 += __shfl_xor(v0, 16, 64);
        v0 += __shfl_xor(v0, 32, 64);
        v1 += __shfl_xor(v1, 16, 64);
        v1 += __shfl_xor(v1, 32, 64);

        const float e0 = ((mb >> (2 * jp)) & 1)     ? __expf(v0 * 0.125f) : 0.f;
        const float e1 = ((mb >> (2 * jp + 1)) & 1) ? __expf(v1 * 0.125f) : 0.f;

        // ---- broadcast e_h within 8-lane group, accumulate in-register ----
#define ACC_H(H)                                                              \
        {                                                                     \
            const float e0h = bcast8<H>(e0);                                  \
            const float e1h = bcast8<H>(e1);                                  \
            accA[H].x += e0h * a0.x + e1h * a1.x;                             \
            accA[H].y += e0h * a0.y + e1h * a1.y;                             \
            accA[H].z += e0h * a0.z + e1h * a1.z;                             \
            accA[H].w += e0h * a0.w + e1h * a1.w;                             \
            accB[H].x += e0h * b0.x + e1h * b1.x;                             \
            accB[H].y += e0h * b0.y + e1h * b1.y;                             \
            accB[H].z += e0h * b0.z + e1h * b1.z;                             \
            accB[H].w += e0h * b0.w + e1h * b1.w;                             \
            ws[H] += e0h + e1h;                                               \
        }
        ACC_H(0) ACC_H(1) ACC_H(2) ACC_H(3) ACC_H(4) ACC_H(5) ACC_H(6) ACC_H(7)
#undef ACC_H

        if (jp < 15) { a0 = na0; b0 = nb0; a1 = na1; b1 = nb1; }
    }

    // ---- cross-wave reduction (2 stages, 32 KB buffer) ----
    if (wave >= 2) {
#pragma unroll
        for (int h = 0; h < HH; ++h) {
            *(float4*)&buf[wave - 2][h][d0]     = accA[h];
            *(float4*)&buf[wave - 2][h][d0 + 4] = accB[h];
        }
    }
    if (lane == 0) {
#pragma unroll
        for (int h = 0; h < HH; ++h) wsb[wave][h] = ws[h];
    }
    __syncthreads();
    if (wave < 2) {
#pragma unroll
        for (int h = 0; h < HH; ++h) {
            float4 u = *(const float4*)&buf[wave][h][d0];
            float4 w2 = *(const float4*)&buf[wave][h][d0 + 4];
            u.x += accA[h].x;  u.y += accA[h].y;  u.z += accA[h].z;  u.w += accA[h].w;
            w2.x += accB[h].x; w2.y += accB[h].y; w2.z += accB[h].z; w2.w += accB[h].w;
            *(float4*)&buf[wave][h][d0]     = u;
            *(float4*)&buf[wave][h][d0 + 4] = w2;
        }
    }
    if (t < HH)
        rsh[t] = 1.0f / (wsb[0][t] + wsb[1][t] + wsb[2][t] + wsb[3][t]);
    __syncthreads();

    float* xbp = xbar + (size_t)sent * (HH * DD);
#pragma unroll
    for (int h = 0; h < HH; ++h) {
        const float r1 = rsh[h];
        xbp[h * DD + t]       = (buf[0][h][t]       + buf[1][h][t])       * r1;
        xbp[h * DD + t + 256] = (buf[0][h][t + 256] + buf[1][h][t + 256]) * r1;
    }
}

// ---------------------------------------------------------------------------
// KZ/KY: 16x64-tile fp32 GEMM, M=512, K=512, register-prefetched across the
// barrier. 256 blocks (32 mb x 8 nb), 256 thr.
//  KZ: A=xbar (am=4096, a_nb=512 head select), B=Wv, bias=bv -> z
//  KY: A=z    (am=512,  a_nb=0),               B=Wo, bias=bo -> y
// ---------------------------------------------------------------------------
__global__ __launch_bounds__(256)
void gemm_tile(const float* __restrict__ A, const int am_stride, const int a_nb_stride,
               const float* __restrict__ B, const float* __restrict__ bias,
               float* __restrict__ C)
{
    __shared__ float As[64][17];   // [k][m]
    __shared__ float Bs[64][68];   // [k][n]

    const int nb = blockIdx.x & 7, mb = blockIdx.x >> 3;
    const int t  = threadIdx.x;
    const int tr = t >> 4, tc = t & 15;

    const float* Ab = A + (size_t)(mb * 16) * am_stride + nb * a_nb_stride
                        + (size_t)tr * am_stride + tc * 4;
    const float* Bb = B + nb * 64 + (size_t)tr * DD + tc * 4;

    float4 ar = *(const float4*)(Ab);
    float4 br0 = *(const float4*)(Bb);
    float4 br1 = *(const float4*)(Bb + 16 * DD);
    float4 br2 = *(const float4*)(Bb + 32 * DD);
    float4 br3 = *(const float4*)(Bb + 48 * DD);

    float a0 = 0.f, a1 = 0.f, a2 = 0.f, a3 = 0.f;

    for (int k0 = 0; k0 < DD; k0 += 64) {
        As[tc * 4 + 0][tr] = ar.x;
        As[tc * 4 + 1][tr] = ar.y;
        As[tc * 4 + 2][tr] = ar.z;
        As[tc * 4 + 3][tr] = ar.w;
        *(float4*)&Bs[tr +  0][tc * 4] = br0;
        *(float4*)&Bs[tr + 16][tc * 4] = br1;
        *(float4*)&Bs[tr + 32][tc * 4] = br2;
        *(float4*)&Bs[tr + 48][tc * 4] = br3;
        __syncthreads();
        if (k0 + 64 < DD) {       // prefetch next K-tile; overlaps compute below
            ar  = *(const float4*)(Ab + k0 + 64);
            br0 = *(const float4*)(Bb + (size_t)(k0 + 64) * DD);
            br1 = *(const float4*)(Bb + (size_t)(k0 + 80) * DD);
            br2 = *(const float4*)(Bb + (size_t)(k0 + 96) * DD);
            br3 = *(const float4*)(Bb + (size_t)(k0 + 112) * DD);
        }
#pragma unroll
        for (int kk = 0; kk < 64; ++kk) {
            const float av = As[kk][tr];
            const float4 bv4 = *(const float4*)&Bs[kk][tc * 4];
            a0 += av * bv4.x; a1 += av * bv4.y; a2 += av * bv4.z; a3 += av * bv4.w;
        }
        __syncthreads();
    }

    const float4 bb = *(const float4*)(bias + nb * 64 + tc * 4);
    float4 o; o.x = a0 + bb.x; o.y = a1 + bb.y; o.z = a2 + bb.z; o.w = a3 + bb.w;
    *(float4*)(C + (size_t)(mb * 16 + tr) * DD + nb * 64 + tc * 4) = o;
}

// ---------------------------------------------------------------------------
// KB: broadcast y[sent] to all 128 token rows of out. 2048 blocks x 256 thr.
// ---------------------------------------------------------------------------
__global__ __launch_bounds__(256)
void kb_bcast(const float* __restrict__ y, float* __restrict__ outp)
{
    const int sent = blockIdx.x >> 2, q = blockIdx.x & 3;
    const int c4 = threadIdx.x & 127;       // float4 column 0..127
    const int rr = threadIdx.x >> 7;        // 0..1
    const float4 yv = *(const float4*)(y + (size_t)sent * DD + c4 * 4);
    float* w0 = outp + (size_t)sent * SENT_STRIDE + (size_t)(q * 32 + rr) * DD + c4 * 4;
#pragma unroll
    for (int i = 0; i < 16; ++i)
        *(float4*)(w0 + (size_t)(i * 2) * DD) = yv;
}

extern "C" void kernel_launch(void* const* d_in, const int* in_sizes, int n_in,
                              void* d_out, int out_size, void* d_ws, size_t ws_size,
                              hipStream_t stream) {
    const float* x    = (const float*)d_in[0];
    const int*   mask = (const int*)  d_in[1];
    // d_in[2]=Wq, d_in[3]=bq dead (token softmax over singleton); d_in[5]=bk shift-invariant
    const float* Wk   = (const float*)d_in[4];
    const float* Wv   = (const float*)d_in[6];
    const float* bv   = (const float*)d_in[7];
    const float* sq   = (const float*)d_in[8];
    const float* Wo   = (const float*)d_in[9];
    const float* bo   = (const float*)d_in[10];
    float* out = (float*)d_out;
    float* ws  = (float*)d_ws;

    float* wk_t = ws + WK_OFF;
    float* xbar = ws + XB_OFF;
    float* z    = ws + Z_OFF;
    float* y    = ws + YY_OFF;

    precompute_wk<<<HH, DD, 0, stream>>>(Wk, sq, wk_t);
    ka_fused<<<NSENT, 256, 0, stream>>>(x, mask, wk_t, xbar);
    gemm_tile<<<256, 256, 0, stream>>>(xbar, HH * DD, DD, Wv, bv, z);
    gemm_tile<<<256, 256, 0, stream>>>(z, DD, 0, Wo, bo, y);
    kb_bcast<<<NSENT * 4, 256, 0, stream>>>(y, out);
}